// Round 1
// baseline (391.258 us; speedup 1.0000x reference)
//
#include <hip/hip_runtime.h>

#define Bn 256
#define Sn 4096
#define Fn 64
#define TCOST 0.0003f
#define INIT_CAP 500.0f

// Output layout (floats):
//   equity      : [B, S+1]        offset 0
//   positions   : [B, S+1, 3]     offset B*(S+1)
//   predictions : [B, S]          offset B*(S+1)*4
//   position_sz : [B]             offset B*(S+1)*4 + B*S
#define EQ_OFF   0
#define POS_OFF  (Bn * (Sn + 1))
#define PRED_OFF (Bn * (Sn + 1) * 4)
#define PSZ_OFF  (PRED_OFF + Bn * Sn)

// Kernel A: wave-cooperative. 16 lanes own one (b,s) row (16 lanes x float4 =
// 64 floats), 4 rows per wave, 16 rows per 256-thread block pass, 4 passes ->
// 64 rows per block. Every feature load instruction is one contiguous 1 KiB
// wave access (vs 64 scattered lines in the per-thread-row version).
#define ROWS_PB 64

__global__ __launch_bounds__(256) void trishot_fwd(
    const float* __restrict__ feat,     // [B, S, F]
    const float* __restrict__ w,        // [F]
    const float* __restrict__ p_lt, const float* __restrict__ p_st,
    const float* __restrict__ p_bps, const float* __restrict__ p_cs,
    const float* __restrict__ p_vi, const float* __restrict__ p_vct,
    const float* __restrict__ p_vst,
    const float* __restrict__ gumbel,   // [S, B, 3]
    float* __restrict__ out)
{
    const int tid  = threadIdx.x;
    const int lane = tid & 63;
    const int wave = tid >> 6;          // 0..3
    const int sub  = lane & 15;         // position within 16-lane row group
    const int grp  = lane >> 4;         // 0..3: row within wave

    const float LT = *p_lt, ST = *p_st, BPS = *p_bps, CS = *p_cs,
                VI = *p_vi, VCT = *p_vct, VST = *p_vst;

    // each lane's slice of the weight vector (constant across rows)
    const float4 wv = ((const float4*)w)[sub];

    const size_t r0 = (size_t)blockIdx.x * ROWS_PB;

#pragma unroll
    for (int pass = 0; pass < ROWS_PB / 16; ++pass) {
        const size_t row = r0 + (size_t)pass * 16 + (size_t)(wave * 4 + grp);
        const float4 fv = ((const float4*)feat)[row * 16 + sub];

        float x = fv.x * wv.x + fv.y * wv.y + fv.z * wv.z + fv.w * wv.w;
        // butterfly sum within each 16-lane group (masks < 16 never cross grp)
        x += __shfl_xor(x, 1);
        x += __shfl_xor(x, 2);
        x += __shfl_xor(x, 4);
        x += __shfl_xor(x, 8);

        if (sub == 0) {
            // this lane's float4 is elements 0..3 of the row: mom,vix,dvix,mret
            const int b = (int)(row >> 12);           // S = 4096 = 2^12
            const int s = (int)(row & (Sn - 1));

            const float p = 1.0f / (1.0f + __expf(-x));
            const float mom = fv.x, vix = fv.y, dvix = fv.z, mret = fv.w;

            const float ss = fabsf(p - 0.5f) * 2.0f;
            const bool collapse = (dvix < -VCT) && (vix < 30.0f);
            const bool spike    = (dvix >  VST) && (vix > 20.0f);
            float psz = fminf(fmaxf(BPS + CS * ss, 0.2f), 1.0f);
            if (collapse || spike) psz *= (1.0f + VI);

            const bool lp = ((p >= LT) && (mom > 0.0f)) || collapse;
            const bool sp = ((p <= ST) && (mom < 0.0f)) || spike;
            const float l0 = lp ? 1.0f : -10.0f;
            const float l1 = sp ? 1.0f : -10.0f;
            const float l2 = (!lp && !sp) ? 1.0f : -10.0f;

            const float* g = gumbel + ((size_t)s * Bn + b) * 3;
            const float z0 = l0 + g[0], z1 = l1 + g[1], z2 = l2 + g[2];
            const float zm = fmaxf(z0, fmaxf(z1, z2));
            const float e0 = __expf(z0 - zm), e1 = __expf(z1 - zm),
                        e2 = __expf(z2 - zm);
            const float inv = 1.0f / (e0 + e1 + e2);
            const float q0 = e0 * inv, q1 = e1 * inv, q2 = e2 * inv;

            out[PRED_OFF + row] = p;

            const size_t prow = ((size_t)b * (Sn + 1) + s + 1) * 3;
            float* pos = out + POS_OFF;
            pos[prow + 0] = q0;
            pos[prow + 1] = q1;
            pos[prow + 2] = q2;

            // stage ret_part into equity cell [b][s+1] (kernel B overwrites)
            out[EQ_OFF + (size_t)b * (Sn + 1) + s + 1] = psz * (q0 - q1) * mret;

            if (s == 0) {
                const size_t p0row = (size_t)b * (Sn + 1) * 3;
                pos[p0row + 0] = 0.0f;
                pos[p0row + 1] = 0.0f;
                pos[p0row + 2] = 1.0f;
            }
            if (s == Sn - 1) {
                out[PSZ_OFF + b] = psz;
            }
        }
    }
}

// Kernel B: one block per batch element. Coalesced factor computation into
// padded LDS, chunked product + Hillis-Steele scan, coalesced write-out.
#define TB  512
#define CHB 8      // 512 * 8 = 4096
#define PAD(i) ((i) + ((i) >> 4))   // +1 slot per 16 to break bank conflicts

__global__ __launch_bounds__(TB) void trishot_scan(float* __restrict__ out)
{
    const int b = blockIdx.x;
    const int j = threadIdx.x;

    float* eq = out + EQ_OFF + (size_t)b * (Sn + 1);
    const float* pos = out + POS_OFF + (size_t)b * (Sn + 1) * 3;

    __shared__ float sfac[Sn + Sn / 16];   // 4352 floats, padded
    __shared__ float sc[TB];

    // phase 1: coalesced reads of pos rows i and i+1 -> factor i (i in [0,Sn))
    for (int i = j; i < Sn; i += TB) {
        const float a0 = pos[(size_t)i * 3 + 0];
        const float a1 = pos[(size_t)i * 3 + 1];
        const float a2 = pos[(size_t)i * 3 + 2];
        const float c0 = pos[(size_t)(i + 1) * 3 + 0];
        const float c1 = pos[(size_t)(i + 1) * 3 + 1];
        const float c2 = pos[(size_t)(i + 1) * 3 + 2];
        const float pc = fabsf(c0 - a0) + fabsf(c1 - a1) + fabsf(c2 - a2);
        const float rp = eq[i + 1];        // staged ret_part
        sfac[PAD(i)] = 1.0f + rp - pc * TCOST;
    }
    __syncthreads();

    // phase 2: per-thread chunk product (padded LDS -> conflict-light)
    float f[CHB];
    float lprod = 1.0f;
    const int t0 = j * CHB;
#pragma unroll
    for (int i = 0; i < CHB; ++i) {
        const float v = sfac[PAD(t0 + i)];
        f[i] = v;
        lprod *= v;
    }
    sc[j] = lprod;
    __syncthreads();

    // phase 3: Hillis-Steele inclusive scan (product) over TB chunk products
#pragma unroll
    for (int off = 1; off < TB; off <<= 1) {
        const float mine  = sc[j];
        const float other = (j >= off) ? sc[j - off] : 1.0f;
        __syncthreads();
        sc[j] = mine * other;
        __syncthreads();
    }

    // phase 4: per-thread running equity back into LDS, then coalesced store
    float eqv = INIT_CAP * ((j > 0) ? sc[j - 1] : 1.0f);
#pragma unroll
    for (int i = 0; i < CHB; ++i) {
        eqv *= f[i];
        sfac[PAD(t0 + i)] = eqv;
    }
    __syncthreads();
    for (int i = j; i < Sn; i += TB) {
        eq[i + 1] = sfac[PAD(i)];
    }
    if (j == 0) eq[0] = INIT_CAP;
}

extern "C" void kernel_launch(void* const* d_in, const int* in_sizes, int n_in,
                              void* d_out, int out_size, void* d_ws, size_t ws_size,
                              hipStream_t stream) {
    const float* feat   = (const float*)d_in[0];
    const float* w      = (const float*)d_in[1];
    const float* lt     = (const float*)d_in[2];
    const float* st     = (const float*)d_in[3];
    const float* bps    = (const float*)d_in[4];
    const float* cs     = (const float*)d_in[5];
    const float* vi     = (const float*)d_in[6];
    const float* vct    = (const float*)d_in[7];
    const float* vst    = (const float*)d_in[8];
    const float* gumbel = (const float*)d_in[9];
    float* out = (float*)d_out;

    trishot_fwd<<<(Bn * Sn) / ROWS_PB, 256, 0, stream>>>(
        feat, w, lt, st, bps, cs, vi, vct, vst, gumbel, out);
    trishot_scan<<<Bn, TB, 0, stream>>>(out);
}